// Round 12
// baseline (248.406 us; speedup 1.0000x reference)
//
#include <hip/hip_runtime.h>
#include <math.h>

#define NN 16000
#define NE 256000
#define INV_SQRT_HD 0.35355339059327373f
#define LN_EPS 1e-5f

typedef __attribute__((ext_vector_type(8))) short bf16x8;
typedef __attribute__((ext_vector_type(4))) float f32x4;
typedef _Float16 half8_ __attribute__((ext_vector_type(8)));
typedef _Float16 half4_ __attribute__((ext_vector_type(4)));

__device__ inline unsigned short f2bf(float x) {
    unsigned u = __float_as_uint(x);
    unsigned r = ((u >> 16) & 1u) + 0x7FFFu;
    return (unsigned short)((u + r) >> 16);
}
__device__ inline float bf2f(unsigned short u) {
    return __uint_as_float(((unsigned)u) << 16);
}

// ---------------- prep: h->bf16, feats pack (LDS-coalesced), ew sigmoid, weight packing ----------------
// GEMM-feats K=32: [feats 0..23][zero 24..31]
// Node GEMMs: Hd uses W1 rows 24..151 (hi), Hs uses rows 152..279 (hj); cols = [kW1 128 | vW1 128]
__global__ __launch_bounds__(256) void prep_kernel(
    const float* __restrict__ h,
    const float* __restrict__ r_feat,
    const float* __restrict__ edge_feat,
    const float* __restrict__ ewW, const float* __restrict__ ewB,
    const float* __restrict__ kW1, const float* __restrict__ vW1,
    const float* __restrict__ kW2, const float* __restrict__ vW2,
    const float* __restrict__ qW1, const float* __restrict__ qW2,
    unsigned short* __restrict__ h_bf, unsigned short* __restrict__ feats_bf,
    float* __restrict__ ew_pre,
    unsigned short* __restrict__ w1fp, unsigned short* __restrict__ w1d,
    unsigned short* __restrict__ w1s,  unsigned short* __restrict__ w2p,
    unsigned short* __restrict__ w1q,  unsigned short* __restrict__ w2q)
{
    __shared__ float stage[6144];   // rfs 5120 + efs 1024
    const int b = blockIdx.x, t = threadIdx.x;
    if (b < 1000) {
        const int gid = b * 256 + t;
        const float4* hp = (const float4*)(h + (size_t)gid * 8);
        float4 a = hp[0], c = hp[1];
        ushort4 u0, u1;
        u0.x = f2bf(a.x); u0.y = f2bf(a.y); u0.z = f2bf(a.z); u0.w = f2bf(a.w);
        u1.x = f2bf(c.x); u1.y = f2bf(c.y); u1.z = f2bf(c.z); u1.w = f2bf(c.w);
        *(ushort4*)(h_bf + (size_t)gid * 8) = u0;
        *(ushort4*)(h_bf + (size_t)gid * 8 + 4) = u1;
    } else if (b < 2000) {
        const int eb2 = (b - 1000) * 256;
        float* rfs = stage;
        float* efs = stage + 5120;
        #pragma unroll
        for (int i = 0; i < 5; ++i) {
            const int idx = i * 1024 + t * 4;
            *(float4*)&rfs[idx] = *(const float4*)(r_feat + (size_t)eb2 * 20 + idx);
        }
        *(float4*)&efs[t * 4] = *(const float4*)(edge_feat + (size_t)eb2 * 4 + t * 4);
        __syncthreads();
        const int e = eb2 + t;
        float rf[20];
        #pragma unroll
        for (int i = 0; i < 20; ++i) rf[i] = rfs[t * 20 + i];
        float z = ewB[0];
        #pragma unroll
        for (int i = 0; i < 20; ++i) z = fmaf(rf[i], ewW[i], z);
        ew_pre[e] = (1.f / (1.f + expf(-z))) * (1.f / 16.f);
        unsigned short fb[32];
        fb[0] = f2bf(efs[t*4+0]); fb[1] = f2bf(efs[t*4+1]);
        fb[2] = f2bf(efs[t*4+2]); fb[3] = f2bf(efs[t*4+3]);
        #pragma unroll
        for (int i = 0; i < 20; ++i) fb[4 + i] = f2bf(rf[i]);
        #pragma unroll
        for (int i = 24; i < 32; ++i) fb[i] = 0;
        #pragma unroll
        for (int i = 0; i < 4; ++i)
            *(int4*)(feats_bf + (size_t)e * 32 + i * 8) = *(int4*)&fb[i * 8];
    } else {
        const int idx = (b - 2000) * 256 + t;   // 488*256 = 124928
        if (idx < 8192) {
            int j = idx & 7, l = (idx >> 3) & 63, mtc = (idx >> 9) & 15;
            int kp = (l >> 4) * 8 + j;
            int col = mtc * 16 + (l & 15);
            float v = 0.f;
            if (kp < 24) v = (col < 128) ? kW1[(size_t)kp * 128 + col]
                                         : vW1[(size_t)kp * 128 + col - 128];
            w1fp[idx] = f2bf(v);
        } else if (idx < 40960) {
            int i = idx - 8192;
            int j = i & 7, l = (i >> 3) & 63, mt = (i >> 9) & 15, s = i >> 13;
            int k = s * 32 + (l >> 4) * 8 + j;
            int col = mt * 16 + (l & 15);
            int row = 24 + k;
            float v = (col < 128) ? kW1[(size_t)row * 128 + col]
                                  : vW1[(size_t)row * 128 + col - 128];
            w1d[i] = f2bf(v);
        } else if (idx < 73728) {
            int i = idx - 40960;
            int j = i & 7, l = (i >> 3) & 63, mt = (i >> 9) & 15, s = i >> 13;
            int k = s * 32 + (l >> 4) * 8 + j;
            int col = mt * 16 + (l & 15);
            int row = 152 + k;
            float v = (col < 128) ? kW1[(size_t)row * 128 + col]
                                  : vW1[(size_t)row * 128 + col - 128];
            w1s[i] = f2bf(v);
        } else if (idx < 92160) {
            int i2 = idx - 73728;
            int j = i2 & 7, l = (i2 >> 3) & 63, sc = i2 >> 9;
            int ct = sc % 9, s2 = sc / 9;
            int k = s2 * 32 + (l >> 4) * 8 + j;
            float v = (ct < 8) ? kW2[(size_t)k * 128 + ct * 16 + (l & 15)]
                               : vW2[(size_t)k * 16 + (l & 15)];
            w2p[i2] = f2bf(v);
        } else if (idx < 108544) {
            int i3 = idx - 92160;
            int j = i3 & 7, l = (i3 >> 3) & 63, mt = (i3 >> 9) & 7, s = i3 >> 12;
            int k = s * 32 + (l >> 4) * 8 + j;
            w1q[i3] = f2bf(qW1[(size_t)k * 128 + mt * 16 + (l & 15)]);
        } else if (idx < 124928) {
            int i4 = idx - 108544;
            int j = i4 & 7, l = (i4 >> 3) & 63, mt = (i4 >> 9) & 7, s = i4 >> 12;
            int k = s * 32 + (l >> 4) * 8 + j;
            w2q[i4] = f2bf(qW2[(size_t)k * 128 + mt * 16 + (l & 15)]);
        }
    }
}

// ---------------- hprep: Hd = h@W1[hi], Hs = h@W1[hj]  (N x 256 fp16 each) ----------------
__global__ __launch_bounds__(256, 2) void hprep_kernel(
    const unsigned short* __restrict__ h_bf,
    const unsigned short* __restrict__ w1d, const unsigned short* __restrict__ w1s,
    unsigned short* __restrict__ Hd, unsigned short* __restrict__ Hs)
{
    const int t = threadIdx.x, nb = blockIdx.x * 32;
    const int wc = t >> 6, l = t & 63, lrow = l & 15, lgrp = l >> 4;

    unsigned offN[2];
    #pragma unroll
    for (int nt = 0; nt < 2; ++nt)
        offN[nt] = (unsigned)(nb + nt * 16 + lrow) * 128 + lgrp * 8;

    f32x4 ad[4][2], as2[4][2];
    #pragma unroll
    for (int mt = 0; mt < 4; ++mt)
        #pragma unroll
        for (int nt = 0; nt < 2; ++nt) {
            ad[mt][nt][0] = 0.f; ad[mt][nt][1] = 0.f; ad[mt][nt][2] = 0.f; ad[mt][nt][3] = 0.f;
            as2[mt][nt][0] = 0.f; as2[mt][nt][1] = 0.f; as2[mt][nt][2] = 0.f; as2[mt][nt][3] = 0.f;
        }
    {
        auto ldA = [&](int s, bf16x8* dD, bf16x8* dS) {
            #pragma unroll
            for (int mt = 0; mt < 4; ++mt) {
                dD[mt] = *(const bf16x8*)(w1d + (size_t)((s * 16 + wc * 4 + mt) * 64 + l) * 8);
                dS[mt] = *(const bf16x8*)(w1s + (size_t)((s * 16 + wc * 4 + mt) * 64 + l) * 8);
            }
        };
        auto ldB = [&](int s, bf16x8* dst) {
            #pragma unroll
            for (int nt = 0; nt < 2; ++nt)
                dst[nt] = *(const bf16x8*)(h_bf + offN[nt] + s * 32);
        };
        bf16x8 aD[2][4], aS[2][4], bB[2][2];
        ldA(0, aD[0], aS[0]); ldB(0, bB[0]);
        ldA(1, aD[1], aS[1]); ldB(1, bB[1]);
        #pragma unroll
        for (int s = 0; s < 4; ++s) {
            const int c = s & 1;
            #pragma unroll
            for (int mt = 0; mt < 4; ++mt)
                #pragma unroll
                for (int nt = 0; nt < 2; ++nt) {
                    ad[mt][nt]  = __builtin_amdgcn_mfma_f32_16x16x32_bf16(aD[c][mt], bB[c][nt], ad[mt][nt], 0, 0, 0);
                    as2[mt][nt] = __builtin_amdgcn_mfma_f32_16x16x32_bf16(aS[c][mt], bB[c][nt], as2[mt][nt], 0, 0, 0);
                }
            if (s < 2) { ldA(s + 2, aD[c], aS[c]); ldB(s + 2, bB[c]); }
        }
    }
    #pragma unroll
    for (int mt = 0; mt < 4; ++mt) {
        const int cb = wc * 64 + mt * 16 + lgrp * 4;
        #pragma unroll
        for (int nt = 0; nt < 2; ++nt) {
            const int el = nt * 16 + lrow;
            half4_ od, os;
            od[0] = (_Float16)ad[mt][nt][0]; od[1] = (_Float16)ad[mt][nt][1];
            od[2] = (_Float16)ad[mt][nt][2]; od[3] = (_Float16)ad[mt][nt][3];
            os[0] = (_Float16)as2[mt][nt][0]; os[1] = (_Float16)as2[mt][nt][1];
            os[2] = (_Float16)as2[mt][nt][2]; os[3] = (_Float16)as2[mt][nt][3];
            *(half4_*)(Hd + (size_t)(nb + el) * 256 + cb) = od;
            *(half4_*)(Hs + (size_t)(nb + el) * 256 + cb) = os;
        }
    }
}

// ---------------- Kernel A: q = MLP(h) via MFMA, 32 nodes/block; OUTPUT = bf16 ----------------
__global__ __launch_bounds__(256, 4) void qmlp_kernel(
    const unsigned short* __restrict__ h_bf,
    const float* __restrict__ B1, const float* __restrict__ G,
    const float* __restrict__ BE, const float* __restrict__ B2,
    const unsigned short* __restrict__ w1q, const unsigned short* __restrict__ w2q,
    unsigned short* __restrict__ q_bf)
{
    __shared__ __align__(16) unsigned char hsq[8192];
    __shared__ float2 lnb[4][32];
    __shared__ float  gb1[128];
    __shared__ float2 gbe[128];
    __shared__ float  gb2[128];

    const int t = threadIdx.x;
    const int nb = blockIdx.x * 32;
    const int wc = t >> 6, l = t & 63, lrow = l & 15, lgrp = l >> 4;

    if (t < 128) { gb1[t] = B1[t]; gbe[t] = make_float2(G[t], BE[t]); gb2[t] = B2[t]; }

    unsigned offN[2];
    #pragma unroll
    for (int nt = 0; nt < 2; ++nt)
        offN[nt] = (unsigned)(nb + nt * 16 + lrow) * 128 + lgrp * 8;
    __syncthreads();

    f32x4 acc1[2][2];
    #pragma unroll
    for (int mt = 0; mt < 2; ++mt) {
        const int cb = wc * 32 + mt * 16 + lgrp * 4;
        #pragma unroll
        for (int nt = 0; nt < 2; ++nt) {
            acc1[mt][nt][0] = gb1[cb];     acc1[mt][nt][1] = gb1[cb + 1];
            acc1[mt][nt][2] = gb1[cb + 2]; acc1[mt][nt][3] = gb1[cb + 3];
        }
    }
    {
        auto ldA = [&](int s, bf16x8* dst) {
            #pragma unroll
            for (int mt = 0; mt < 2; ++mt)
                dst[mt] = *(const bf16x8*)(w1q + (size_t)((s * 8 + wc * 2 + mt) * 64 + l) * 8);
        };
        auto ldB = [&](int s, bf16x8* dst) {
            #pragma unroll
            for (int nt = 0; nt < 2; ++nt)
                dst[nt] = *(const bf16x8*)(h_bf + offN[nt] + s * 32);
        };
        bf16x8 aB[2][2], bB[2][2];
        ldA(0, aB[0]); ldB(0, bB[0]);
        ldA(1, aB[1]); ldB(1, bB[1]);
        #pragma unroll
        for (int s = 0; s < 4; ++s) {
            const int c = s & 1;
            #pragma unroll
            for (int mt = 0; mt < 2; ++mt)
                #pragma unroll
                for (int nt = 0; nt < 2; ++nt)
                    acc1[mt][nt] = __builtin_amdgcn_mfma_f32_16x16x32_bf16(aB[c][mt], bB[c][nt], acc1[mt][nt], 0, 0, 0);
            if (s < 2) { ldA(s + 2, aB[c]); ldB(s + 2, bB[c]); }
        }
    }

    float2 myln[2];
    #pragma unroll
    for (int nt = 0; nt < 2; ++nt) {
        float p1 = 0.f, p2 = 0.f;
        #pragma unroll
        for (int mt = 0; mt < 2; ++mt)
            #pragma unroll
            for (int r = 0; r < 4; ++r) { float v = acc1[mt][nt][r]; p1 += v; p2 += v * v; }
        p1 += __shfl_xor(p1, 16); p2 += __shfl_xor(p2, 16);
        p1 += __shfl_xor(p1, 32); p2 += __shfl_xor(p2, 32);
        myln[nt] = make_float2(p1, p2);
        if (l < 16) lnb[wc][nt * 16 + l] = myln[nt];
    }
    __syncthreads();

    #pragma unroll
    for (int nt = 0; nt < 2; ++nt) {
        const int el = nt * 16 + lrow;
        float2 a0 = lnb[0][el], a1 = lnb[1][el], a2 = lnb[2][el], a3 = lnb[3][el];
        const float s1 = a0.x + a1.x + a2.x + a3.x;
        const float s2 = a0.y + a1.y + a2.y + a3.y;
        const float mu = s1 * (1.f / 128.f);
        const float rs = rsqrtf(s2 * (1.f / 128.f) - mu * mu + LN_EPS);
        #pragma unroll
        for (int mt = 0; mt < 2; ++mt) {
            const int cb = wc * 32 + mt * 16 + lgrp * 4;
            const float2 g0 = gbe[cb], g1 = gbe[cb+1], g2 = gbe[cb+2], g3 = gbe[cb+3];
            ushort4 u;
            u.x = f2bf(fmaxf((acc1[mt][nt][0] - mu) * rs * g0.x + g0.y, 0.f));
            u.y = f2bf(fmaxf((acc1[mt][nt][1] - mu) * rs * g1.x + g1.y, 0.f));
            u.z = f2bf(fmaxf((acc1[mt][nt][2] - mu) * rs * g2.x + g2.y, 0.f));
            u.w = f2bf(fmaxf((acc1[mt][nt][3] - mu) * rs * g3.x + g3.y, 0.f));
            *(ushort4*)(hsq + ((cb >> 3) * 32 + el) * 16 + (lgrp & 1) * 8) = u;
        }
    }
    __syncthreads();

    f32x4 acc2[2][2];
    #pragma unroll
    for (int km = 0; km < 2; ++km) {
        const int c2 = (wc * 2 + km) * 16 + lgrp * 4;
        #pragma unroll
        for (int nt = 0; nt < 2; ++nt) {
            acc2[km][nt][0] = gb2[c2];     acc2[km][nt][1] = gb2[c2 + 1];
            acc2[km][nt][2] = gb2[c2 + 2]; acc2[km][nt][3] = gb2[c2 + 3];
        }
    }
    {
        bf16x8 a0C = *(const bf16x8*)(w2q + (size_t)((wc * 2) * 64 + l) * 8);
        bf16x8 a1C = *(const bf16x8*)(w2q + (size_t)((wc * 2 + 1) * 64 + l) * 8);
        #pragma unroll
        for (int s2 = 0; s2 < 4; ++s2) {
            bf16x8 a0N, a1N;
            if (s2 < 3) {
                a0N = *(const bf16x8*)(w2q + (size_t)(((s2+1) * 8 + wc * 2) * 64 + l) * 8);
                a1N = *(const bf16x8*)(w2q + (size_t)(((s2+1) * 8 + wc * 2 + 1) * 64 + l) * 8);
            }
            bf16x8 hb[2];
            #pragma unroll
            for (int nt = 0; nt < 2; ++nt)
                hb[nt] = *(const bf16x8*)(hsq + (((s2 * 4 + lgrp) * 32) + nt * 16 + lrow) * 16);
            #pragma unroll
            for (int nt = 0; nt < 2; ++nt) {
                acc2[0][nt] = __builtin_amdgcn_mfma_f32_16x16x32_bf16(a0C, hb[nt], acc2[0][nt], 0, 0, 0);
                acc2[1][nt] = __builtin_amdgcn_mfma_f32_16x16x32_bf16(a1C, hb[nt], acc2[1][nt], 0, 0, 0);
            }
            a0C = a0N; a1C = a1N;
        }
    }
    #pragma unroll
    for (int km = 0; km < 2; ++km) {
        const int c2 = (wc * 2 + km) * 16 + lgrp * 4;
        #pragma unroll
        for (int nt = 0; nt < 2; ++nt) {
            const int el = nt * 16 + lrow;
            ushort4 o;
            o.x = f2bf(acc2[km][nt][0]); o.y = f2bf(acc2[km][nt][1]);
            o.z = f2bf(acc2[km][nt][2]); o.w = f2bf(acc2[km][nt][3]);
            *(ushort4*)(q_bf + (size_t)(nb + el) * 128 + c2) = o;
        }
    }
}

// ------------- Kernel B: edge kernel — direct per-lane Hd/Hs gathers, 2 barriers -------------
__global__ __launch_bounds__(256, 3) void edge_kernel(
    const unsigned short* __restrict__ feats_bf,
    const int*   __restrict__ eidx,
    const float* __restrict__ ew_pre,
    const unsigned short* __restrict__ Hd, const unsigned short* __restrict__ Hs,
    const float* __restrict__ kB1, const float* __restrict__ kG, const float* __restrict__ kBE,
    const float* __restrict__ vB1, const float* __restrict__ vG, const float* __restrict__ vBE,
    const float* __restrict__ kB2, const float* __restrict__ vB2,
    const unsigned short* __restrict__ w1fp, const unsigned short* __restrict__ w2p,
    const unsigned short* __restrict__ q_bf,
    float* __restrict__ ex_out, float* __restrict__ vw_out, float* __restrict__ denom)
{
    __shared__ __align__(16) unsigned char hs[16384];  // hidden: 2 regions x 16 chunks x 32 e x 16B
    __shared__ float2 lnb[4][32];

    const int t = threadIdx.x;
    const int eb = blockIdx.x * 32;
    const int wc = t >> 6, l = t & 63, lrow = l & 15, lgrp = l >> 4;

    // ---- edge indices (L2-hot) ----
    int dst01[2], src01[2];
    #pragma unroll
    for (int nt = 0; nt < 2; ++nt) {
        const int e = eb + nt * 16 + lrow;
        dst01[nt] = eidx[NE + e];
        src01[nt] = eidx[e];
    }

    // ---- direct per-lane gathers: 16 x 8B, all independent, issued up-front ----
    half4_ ghd[4][2], ghs[4][2];
    #pragma unroll
    for (int mt = 0; mt < 4; ++mt) {
        const int cb = wc * 64 + mt * 16 + lgrp * 4;
        #pragma unroll
        for (int nt = 0; nt < 2; ++nt) {
            ghd[mt][nt] = *(const half4_*)(Hd + (size_t)dst01[nt] * 256 + cb);
            ghs[mt][nt] = *(const half4_*)(Hs + (size_t)src01[nt] * 256 + cb);
        }
    }

    // ---- feats B fragment, w1f A fragments, q fragments ----
    bf16x8 bF[2];
    #pragma unroll
    for (int nt = 0; nt < 2; ++nt)
        bF[nt] = *(const bf16x8*)(feats_bf + (size_t)(eb + nt * 16 + lrow) * 32 + lgrp * 8);
    bf16x8 aF[4];
    #pragma unroll
    for (int mt = 0; mt < 4; ++mt)
        aF[mt] = *(const bf16x8*)(w1fp + (size_t)((wc * 4 + mt) * 64 + l) * 8);
    int2 qreg[2][2];
    #pragma unroll
    for (int km = 0; km < 2; ++km)
        #pragma unroll
        for (int nt = 0; nt < 2; ++nt)
            qreg[km][nt] = *(const int2*)(q_bf + (size_t)dst01[nt] * 128 + (wc * 2 + km) * 16 + lgrp * 4);

    // ---- acc init with bias (direct broadcast loads) + feats MFMA + assembly ----
    f32x4 acc1[4][2];
    #pragma unroll
    for (int mt = 0; mt < 4; ++mt) {
        const int cb = wc * 64 + mt * 16 + lgrp * 4;   // 0..255
        const float4 b1 = (cb < 128) ? *(const float4*)(kB1 + cb)
                                     : *(const float4*)(vB1 + cb - 128);
        #pragma unroll
        for (int nt = 0; nt < 2; ++nt) {
            acc1[mt][nt][0] = b1.x; acc1[mt][nt][1] = b1.y;
            acc1[mt][nt][2] = b1.z; acc1[mt][nt][3] = b1.w;
        }
    }
    #pragma unroll
    for (int mt = 0; mt < 4; ++mt)
        #pragma unroll
        for (int nt = 0; nt < 2; ++nt)
            acc1[mt][nt] = __builtin_amdgcn_mfma_f32_16x16x32_bf16(aF[mt], bF[nt], acc1[mt][nt], 0, 0, 0);
    #pragma unroll
    for (int mt = 0; mt < 4; ++mt)
        #pragma unroll
        for (int nt = 0; nt < 2; ++nt) {
            acc1[mt][nt][0] += (float)ghd[mt][nt][0] + (float)ghs[mt][nt][0];
            acc1[mt][nt][1] += (float)ghd[mt][nt][1] + (float)ghs[mt][nt][1];
            acc1[mt][nt][2] += (float)ghd[mt][nt][2] + (float)ghs[mt][nt][2];
            acc1[mt][nt][3] += (float)ghd[mt][nt][3] + (float)ghs[mt][nt][3];
        }

    // ---- LN partials ----
    float2 myln[2];
    #pragma unroll
    for (int nt = 0; nt < 2; ++nt) {
        float p1 = 0.f, p2 = 0.f;
        #pragma unroll
        for (int mt = 0; mt < 4; ++mt)
            #pragma unroll
            for (int r = 0; r < 4; ++r) { float v = acc1[mt][nt][r]; p1 += v; p2 += v * v; }
        p1 += __shfl_xor(p1, 16); p2 += __shfl_xor(p2, 16);
        p1 += __shfl_xor(p1, 32); p2 += __shfl_xor(p2, 32);
        myln[nt] = make_float2(p1, p2);
        if (l < 16) lnb[wc][nt * 16 + l] = myln[nt];
    }
    __syncthreads();   // B1

    // ---- normalize + ReLU + bf16 -> hs (fragment-native); G/BE direct broadcast loads ----
    #pragma unroll
    for (int nt = 0; nt < 2; ++nt) {
        const int el = nt * 16 + lrow;
        const float2 oth = lnb[wc ^ 1][el];
        const float s1 = myln[nt].x + oth.x, s2 = myln[nt].y + oth.y;
        const float mu = s1 * (1.f / 128.f);
        const float rs = rsqrtf(s2 * (1.f / 128.f) - mu * mu + LN_EPS);
        #pragma unroll
        for (int mt = 0; mt < 4; ++mt) {
            const int cb = wc * 64 + mt * 16 + lgrp * 4;
            const int region = cb >> 7, kc = cb & 127;
            const float4 g4  = (cb < 128) ? *(const float4*)(kG + cb)  : *(const float4*)(vG + cb - 128);
            const float4 be4 = (cb < 128) ? *(const float4*)(kBE + cb) : *(const float4*)(vBE + cb - 128);
            ushort4 u;
            u.x = f2bf(fmaxf((acc1[mt][nt][0] - mu) * rs * g4.x + be4.x, 0.f));
            u.y = f2bf(fmaxf((acc1[mt][nt][1] - mu) * rs * g4.y + be4.y, 0.f));
            u.z = f2bf(fmaxf((acc1[mt][nt][2] - mu) * rs * g4.z + be4.z, 0.f));
            u.w = f2bf(fmaxf((acc1[mt][nt][3] - mu) * rs * g4.w + be4.w, 0.f));
            *(ushort4*)(hs + region * 8192 + ((kc >> 3) * 32 + el) * 16 + (lgrp & 1) * 8) = u;
        }
    }
    __syncthreads();   // B2

    // ---- GEMM2: kT[128][32e] + vT[16][32e], K=128 (4 steps), A depth-2 from L2 ----
    f32x4 acc2[2][2], accv;
    #pragma unroll
    for (int km = 0; km < 2; ++km) {
        const int c0b = (wc * 2 + km) * 16 + lgrp * 4;   // < 128
        const float4 b2 = *(const float4*)(kB2 + c0b);
        #pragma unroll
        for (int nt = 0; nt < 2; ++nt) {
            acc2[km][nt][0] = b2.x; acc2[km][nt][1] = b2.y;
            acc2[km][nt][2] = b2.z; acc2[km][nt][3] = b2.w;
        }
    }
    const int vel = wc * 16 + lrow;   // valid when wc<2
    {
        const float4 bv = *(const float4*)(vB2 + lgrp * 4);
        accv[0] = bv.x; accv[1] = bv.y; accv[2] = bv.z; accv[3] = bv.w;
    }
    {
        bf16x8 a0C = *(const bf16x8*)(w2p + (size_t)((wc * 2) * 64 + l) * 8);
        bf16x8 a1C = *(const bf16x8*)(w2p + (size_t)((wc * 2 + 1) * 64 + l) * 8);
        bf16x8 avC = *(const bf16x8*)(w2p + (size_t)(8 * 64 + l) * 8);
        #pragma unroll
        for (int s2 = 0; s2 < 4; ++s2) {
            bf16x8 a0N, a1N, avN;
            if (s2 < 3) {
                a0N = *(const bf16x8*)(w2p + (size_t)(((s2+1) * 9 + wc * 2) * 64 + l) * 8);
                a1N = *(const bf16x8*)(w2p + (size_t)(((s2+1) * 9 + wc * 2 + 1) * 64 + l) * 8);
                avN = *(const bf16x8*)(w2p + (size_t)(((s2+1) * 9 + 8) * 64 + l) * 8);
            }
            bf16x8 hb[2];
            #pragma unroll
            for (int nt = 0; nt < 2; ++nt)
                hb[nt] = *(const bf16x8*)(hs + ((s2 * 4 + lgrp) * 32 + nt * 16 + lrow) * 16);
            #pragma unroll
            for (int nt = 0; nt < 2; ++nt) {
                acc2[0][nt] = __builtin_amdgcn_mfma_f32_16x16x32_bf16(a0C, hb[nt], acc2[0][nt], 0, 0, 0);
                acc2[1][nt] = __builtin_amdgcn_mfma_f32_16x16x32_bf16(a1C, hb[nt], acc2[1][nt], 0, 0, 0);
            }
            if (wc < 2) {
                bf16x8 hv = *(const bf16x8*)(hs + 8192 + ((s2 * 4 + lgrp) * 32 + vel) * 16);
                accv = __builtin_amdgcn_mfma_f32_16x16x32_bf16(avC, hv, accv, 0, 0, 0);
            }
            a0C = a0N; a1C = a1N; avC = avN;
        }
    }

    // ---- v output ----
    if (wc < 2) {
        const float sc = ew_pre[eb + vel];
        float4 vo;
        vo.x = accv[0] * sc; vo.y = accv[1] * sc; vo.z = accv[2] * sc; vo.w = accv[3] * sc;
        *(float4*)(vw_out + (size_t)(eb + vel) * 16 + lgrp * 4) = vo;
    }

    // ---- scores + exp + denom atomics ----
    #pragma unroll
    for (int km = 0; km < 2; ++km) {
        #pragma unroll
        for (int nt = 0; nt < 2; ++nt) {
            const int el = nt * 16 + lrow;
            const int2 qv = qreg[km][nt];
            const float q0 = bf2f((unsigned short)(qv.x & 0xffff));
            const float q1 = bf2f((unsigned short)(((unsigned)qv.x) >> 16));
            const float q2 = bf2f((unsigned short)(qv.y & 0xffff));
            const float q3 = bf2f((unsigned short)(((unsigned)qv.y) >> 16));
            float sp = acc2[km][nt][0] * q0 + acc2[km][nt][1] * q1
                     + acc2[km][nt][2] * q2 + acc2[km][nt][3] * q3;
            sp += __shfl_xor(sp, 16);
            if ((l & 16) == 0) {
                const float exv = expf(sp * INV_SQRT_HD);
                const int hh = (wc * 2 + km) * 2 + (lgrp >> 1);
                ex_out[(size_t)(eb + el) * 16 + hh] = exv;
                atomicAdd(&denom[(size_t)dst01[nt] * 16 + hh], exv);
            }
        }
    }
}

// ------------- Kernel C: alpha = ex/denom, scatter out += sum_h(alpha*vw)*rel_x -------------
__global__ __launch_bounds__(256) void finalize_kernel(
    const int* __restrict__ eidx, const float* __restrict__ relx,
    const float* __restrict__ exb, const float* __restrict__ vwb,
    const float* __restrict__ den, float* __restrict__ out)
{
    const int e = blockIdx.x * 256 + threadIdx.x;
    const int dst = eidx[NE + e];
    const float4* ex4 = (const float4*)(exb + (size_t)e*16);
    const float4* vw4 = (const float4*)(vwb + (size_t)e*16);
    const float4* dn4 = (const float4*)(den + (size_t)dst*16);
    float s = 0.f;
    #pragma unroll
    for (int k = 0; k < 4; ++k) {
        float4 a = ex4[k], b = vw4[k], d = dn4[k];
        s += (a.x/d.x)*b.x + (a.y/d.y)*b.y + (a.z/d.z)*b.z + (a.w/d.w)*b.w;
    }
    float r0 = relx[(size_t)e*3+0], r1 = relx[(size_t)e*3+1], r2 = relx[(size_t)e*3+2];
    atomicAdd(&out[(size_t)dst*3+0], s*r0);
    atomicAdd(&out[(size_t)dst*3+1], s*r1);
    atomicAdd(&out[(size_t)dst*3+2], s*r2);
}

extern "C" void kernel_launch(void* const* d_in, const int* in_sizes, int n_in,
                              void* d_out, int out_size, void* d_ws, size_t ws_size,
                              hipStream_t stream) {
    const float* h         = (const float*)d_in[0];
    const float* rel_x     = (const float*)d_in[1];
    const float* r_feat    = (const float*)d_in[2];
    const float* edge_feat = (const float*)d_in[3];
    const int*   eidx      = (const int*)  d_in[4];
    const float* kW1 = (const float*)d_in[5];
    const float* kB1 = (const float*)d_in[6];
    const float* kG  = (const float*)d_in[7];
    const float* kBE = (const float*)d_in[8];
    const float* kW2 = (const float*)d_in[9];
    const float* kB2 = (const float*)d_in[10];
    const float* vW1 = (const float*)d_in[11];
    const float* vB1 = (const float*)d_in[12];
    const float* vG  = (const float*)d_in[13];
    const float* vBE = (const float*)d_in[14];
    const float* vW2 = (const float*)d_in[15];
    const float* vB2 = (const float*)d_in[16];
    const float* qW1 = (const float*)d_in[17];
    const float* qB1 = (const float*)d_in[18];
    const float* qG  = (const float*)d_in[19];
    const float* qBE = (const float*)d_in[20];
    const float* qW2 = (const float*)d_in[21];
    const float* qB2 = (const float*)d_in[22];
    const float* ewW = (const float*)d_in[23];
    const float* ewB = (const float*)d_in[24];

    float* ws   = (float*)d_ws;
    float* qbuf = ws;                             // bf16 q lives here (N*128)
    float* exb  = qbuf + (size_t)NN*128;          // E*16
    float* vwb  = exb + (size_t)NE*16;            // E*16
    float* den  = vwb + (size_t)NE*16;            // N*16
    float* ewp  = den + (size_t)NN*16;            // E
    unsigned short* w1fp = (unsigned short*)(ewp + (size_t)NE);   // 8192
    unsigned short* w1d  = w1fp + 8192;                           // 32768
    unsigned short* w1s  = w1d + 32768;                           // 32768
    unsigned short* w2p  = w1s + 32768;                           // 18432
    unsigned short* w1q  = w2p + 18432;                           // 16384
    unsigned short* w2q  = w1q + 16384;                           // 16384
    unsigned short* h_bf = w2q + 16384;                           // N*128
    unsigned short* feats_bf = h_bf + (size_t)NN*128;             // E*32
    unsigned short* Hd   = feats_bf + (size_t)NE*32;              // N*256 fp16
    unsigned short* Hs   = Hd + (size_t)NN*256;                   // N*256 fp16
    unsigned short* q_bf = (unsigned short*)qbuf;                 // N*128 bf16
    float* outf = (float*)d_out;

    hipMemsetAsync(den, 0, (size_t)NN*16*sizeof(float), stream);
    hipMemsetAsync(outf, 0, (size_t)NN*3*sizeof(float), stream);

    prep_kernel<<<2488, 256, 0, stream>>>(h, r_feat, edge_feat, ewW, ewB,
                                          kW1, vW1, kW2, vW2, qW1, qW2,
                                          h_bf, feats_bf, ewp,
                                          w1fp, w1d, w1s, w2p, w1q, w2q);
    hprep_kernel<<<NN/32, 256, 0, stream>>>(h_bf, w1d, w1s, Hd, Hs);
    qmlp_kernel<<<NN/32, 256, 0, stream>>>(h_bf, qB1, qG, qBE, qB2, w1q, w2q, q_bf);
    edge_kernel<<<NE/32, 256, 0, stream>>>(feats_bf, eidx, ewp,
                                           Hd, Hs,
                                           kB1, kG, kBE, vB1, vG, vBE,
                                           kB2, vB2, w1fp, w2p, q_bf,
                                           exb, vwb, den);
    finalize_kernel<<<NE/256, 256, 0, stream>>>(eidx, rel_x, exb, vwb, den, outf);
}

// Round 13
// 220.396 us; speedup vs baseline: 1.1271x; 1.1271x over previous
//
#include <hip/hip_runtime.h>
#include <math.h>

#define NN 16000
#define NE 256000
#define INV_SQRT_HD 0.35355339059327373f
#define LN_EPS 1e-5f

typedef __attribute__((ext_vector_type(8))) short bf16x8;
typedef __attribute__((ext_vector_type(4))) float f32x4;
typedef _Float16 half8_ __attribute__((ext_vector_type(8)));
typedef _Float16 half4_ __attribute__((ext_vector_type(4)));

__device__ inline unsigned short f2bf(float x) {
    unsigned u = __float_as_uint(x);
    unsigned r = ((u >> 16) & 1u) + 0x7FFFu;
    return (unsigned short)((u + r) >> 16);
}
__device__ inline float bf2f(unsigned short u) {
    return __uint_as_float(((unsigned)u) << 16);
}

// ---------------- prep: h->bf16, feats pack (LDS-coalesced), ew sigmoid, weight packing ----------------
__global__ __launch_bounds__(256) void prep_kernel(
    const float* __restrict__ h,
    const float* __restrict__ r_feat,
    const float* __restrict__ edge_feat,
    const float* __restrict__ ewW, const float* __restrict__ ewB,
    const float* __restrict__ kW1, const float* __restrict__ vW1,
    const float* __restrict__ kW2, const float* __restrict__ vW2,
    const float* __restrict__ qW1, const float* __restrict__ qW2,
    unsigned short* __restrict__ h_bf, unsigned short* __restrict__ feats_bf,
    float* __restrict__ ew_pre,
    unsigned short* __restrict__ w1fp, unsigned short* __restrict__ w1d,
    unsigned short* __restrict__ w1s,  unsigned short* __restrict__ w2p,
    unsigned short* __restrict__ w1q,  unsigned short* __restrict__ w2q)
{
    __shared__ float stage[6144];   // rfs 5120 + efs 1024
    const int b = blockIdx.x, t = threadIdx.x;
    if (b < 1000) {
        const int gid = b * 256 + t;
        const float4* hp = (const float4*)(h + (size_t)gid * 8);
        float4 a = hp[0], c = hp[1];
        ushort4 u0, u1;
        u0.x = f2bf(a.x); u0.y = f2bf(a.y); u0.z = f2bf(a.z); u0.w = f2bf(a.w);
        u1.x = f2bf(c.x); u1.y = f2bf(c.y); u1.z = f2bf(c.z); u1.w = f2bf(c.w);
        *(ushort4*)(h_bf + (size_t)gid * 8) = u0;
        *(ushort4*)(h_bf + (size_t)gid * 8 + 4) = u1;
    } else if (b < 2000) {
        const int eb2 = (b - 1000) * 256;
        float* rfs = stage;
        float* efs = stage + 5120;
        #pragma unroll
        for (int i = 0; i < 5; ++i) {
            const int idx = i * 1024 + t * 4;
            *(float4*)&rfs[idx] = *(const float4*)(r_feat + (size_t)eb2 * 20 + idx);
        }
        *(float4*)&efs[t * 4] = *(const float4*)(edge_feat + (size_t)eb2 * 4 + t * 4);
        __syncthreads();
        const int e = eb2 + t;
        float rf[20];
        #pragma unroll
        for (int i = 0; i < 20; ++i) rf[i] = rfs[t * 20 + i];
        float z = ewB[0];
        #pragma unroll
        for (int i = 0; i < 20; ++i) z = fmaf(rf[i], ewW[i], z);
        ew_pre[e] = (1.f / (1.f + expf(-z))) * (1.f / 16.f);
        unsigned short fb[32];
        fb[0] = f2bf(efs[t*4+0]); fb[1] = f2bf(efs[t*4+1]);
        fb[2] = f2bf(efs[t*4+2]); fb[3] = f2bf(efs[t*4+3]);
        #pragma unroll
        for (int i = 0; i < 20; ++i) fb[4 + i] = f2bf(rf[i]);
        #pragma unroll
        for (int i = 24; i < 32; ++i) fb[i] = 0;
        #pragma unroll
        for (int i = 0; i < 4; ++i)
            *(int4*)(feats_bf + (size_t)e * 32 + i * 8) = *(int4*)&fb[i * 8];
    } else {
        const int idx = (b - 2000) * 256 + t;
        if (idx < 8192) {
            int j = idx & 7, l = (idx >> 3) & 63, mtc = (idx >> 9) & 15;
            int kp = (l >> 4) * 8 + j;
            int col = mtc * 16 + (l & 15);
            float v = 0.f;
            if (kp < 24) v = (col < 128) ? kW1[(size_t)kp * 128 + col]
                                         : vW1[(size_t)kp * 128 + col - 128];
            w1fp[idx] = f2bf(v);
        } else if (idx < 40960) {
            int i = idx - 8192;
            int j = i & 7, l = (i >> 3) & 63, mt = (i >> 9) & 15, s = i >> 13;
            int k = s * 32 + (l >> 4) * 8 + j;
            int col = mt * 16 + (l & 15);
            int row = 24 + k;
            float v = (col < 128) ? kW1[(size_t)row * 128 + col]
                                  : vW1[(size_t)row * 128 + col - 128];
            w1d[i] = f2bf(v);
        } else if (idx < 73728) {
            int i = idx - 40960;
            int j = i & 7, l = (i >> 3) & 63, mt = (i >> 9) & 15, s = i >> 13;
            int k = s * 32 + (l >> 4) * 8 + j;
            int col = mt * 16 + (l & 15);
            int row = 152 + k;
            float v = (col < 128) ? kW1[(size_t)row * 128 + col]
                                  : vW1[(size_t)row * 128 + col - 128];
            w1s[i] = f2bf(v);
        } else if (idx < 92160) {
            int i2 = idx - 73728;
            int j = i2 & 7, l = (i2 >> 3) & 63, sc = i2 >> 9;
            int ct = sc % 9, s2 = sc / 9;
            int k = s2 * 32 + (l >> 4) * 8 + j;
            float v = (ct < 8) ? kW2[(size_t)k * 128 + ct * 16 + (l & 15)]
                               : vW2[(size_t)k * 16 + (l & 15)];
            w2p[i2] = f2bf(v);
        } else if (idx < 108544) {
            int i3 = idx - 92160;
            int j = i3 & 7, l = (i3 >> 3) & 63, mt = (i3 >> 9) & 7, s = i3 >> 12;
            int k = s * 32 + (l >> 4) * 8 + j;
            w1q[i3] = f2bf(qW1[(size_t)k * 128 + mt * 16 + (l & 15)]);
        } else if (idx < 124928) {
            int i4 = idx - 108544;
            int j = i4 & 7, l = (i4 >> 3) & 63, mt = (i4 >> 9) & 7, s = i4 >> 12;
            int k = s * 32 + (l >> 4) * 8 + j;
            w2q[i4] = f2bf(qW2[(size_t)k * 128 + mt * 16 + (l & 15)]);
        }
    }
}

// ---------------- hprep: Hd = h@W1[hi], Hs = h@W1[hj]  (N x 256 fp16 each) ----------------
__global__ __launch_bounds__(256, 2) void hprep_kernel(
    const unsigned short* __restrict__ h_bf,
    const unsigned short* __restrict__ w1d, const unsigned short* __restrict__ w1s,
    unsigned short* __restrict__ Hd, unsigned short* __restrict__ Hs)
{
    const int t = threadIdx.x, nb = blockIdx.x * 32;
    const int wc = t >> 6, l = t & 63, lrow = l & 15, lgrp = l >> 4;

    unsigned offN[2];
    #pragma unroll
    for (int nt = 0; nt < 2; ++nt)
        offN[nt] = (unsigned)(nb + nt * 16 + lrow) * 128 + lgrp * 8;

    f32x4 ad[4][2], as2[4][2];
    #pragma unroll
    for (int mt = 0; mt < 4; ++mt)
        #pragma unroll
        for (int nt = 0; nt < 2; ++nt) {
            ad[mt][nt][0] = 0.f; ad[mt][nt][1] = 0.f; ad[mt][nt][2] = 0.f; ad[mt][nt][3] = 0.f;
            as2[mt][nt][0] = 0.f; as2[mt][nt][1] = 0.f; as2[mt][nt][2] = 0.f; as2[mt][nt][3] = 0.f;
        }
    {
        auto ldA = [&](int s, bf16x8* dD, bf16x8* dS) {
            #pragma unroll
            for (int mt = 0; mt < 4; ++mt) {
                dD[mt] = *(const bf16x8*)(w1d + (size_t)((s * 16 + wc * 4 + mt) * 64 + l) * 8);
                dS[mt] = *(const bf16x8*)(w1s + (size_t)((s * 16 + wc * 4 + mt) * 64 + l) * 8);
            }
        };
        auto ldB = [&](int s, bf16x8* dst) {
            #pragma unroll
            for (int nt = 0; nt < 2; ++nt)
                dst[nt] = *(const bf16x8*)(h_bf + offN[nt] + s * 32);
        };
        bf16x8 aD[2][4], aS[2][4], bB[2][2];
        ldA(0, aD[0], aS[0]); ldB(0, bB[0]);
        ldA(1, aD[1], aS[1]); ldB(1, bB[1]);
        #pragma unroll
        for (int s = 0; s < 4; ++s) {
            const int c = s & 1;
            #pragma unroll
            for (int mt = 0; mt < 4; ++mt)
                #pragma unroll
                for (int nt = 0; nt < 2; ++nt) {
                    ad[mt][nt]  = __builtin_amdgcn_mfma_f32_16x16x32_bf16(aD[c][mt], bB[c][nt], ad[mt][nt], 0, 0, 0);
                    as2[mt][nt] = __builtin_amdgcn_mfma_f32_16x16x32_bf16(aS[c][mt], bB[c][nt], as2[mt][nt], 0, 0, 0);
                }
            if (s < 2) { ldA(s + 2, aD[c], aS[c]); ldB(s + 2, bB[c]); }
        }
    }
    #pragma unroll
    for (int mt = 0; mt < 4; ++mt) {
        const int cb = wc * 64 + mt * 16 + lgrp * 4;
        #pragma unroll
        for (int nt = 0; nt < 2; ++nt) {
            const int el = nt * 16 + lrow;
            half4_ od, os;
            od[0] = (_Float16)ad[mt][nt][0]; od[1] = (_Float16)ad[mt][nt][1];
            od[2] = (_Float16)ad[mt][nt][2]; od[3] = (_Float16)ad[mt][nt][3];
            os[0] = (_Float16)as2[mt][nt][0]; os[1] = (_Float16)as2[mt][nt][1];
            os[2] = (_Float16)as2[mt][nt][2]; os[3] = (_Float16)as2[mt][nt][3];
            *(half4_*)(Hd + (size_t)(nb + el) * 256 + cb) = od;
            *(half4_*)(Hs + (size_t)(nb + el) * 256 + cb) = os;
        }
    }
}

// ---------------- Kernel A: q = MLP(h) via MFMA, 32 nodes/block; OUTPUT = bf16 ----------------
__global__ __launch_bounds__(256, 4) void qmlp_kernel(
    const unsigned short* __restrict__ h_bf,
    const float* __restrict__ B1, const float* __restrict__ G,
    const float* __restrict__ BE, const float* __restrict__ B2,
    const unsigned short* __restrict__ w1q, const unsigned short* __restrict__ w2q,
    unsigned short* __restrict__ q_bf)
{
    __shared__ __align__(16) unsigned char hsq[8192];
    __shared__ float2 lnb[4][32];
    __shared__ float  gb1[128];
    __shared__ float2 gbe[128];
    __shared__ float  gb2[128];

    const int t = threadIdx.x;
    const int nb = blockIdx.x * 32;
    const int wc = t >> 6, l = t & 63, lrow = l & 15, lgrp = l >> 4;

    if (t < 128) { gb1[t] = B1[t]; gbe[t] = make_float2(G[t], BE[t]); gb2[t] = B2[t]; }

    unsigned offN[2];
    #pragma unroll
    for (int nt = 0; nt < 2; ++nt)
        offN[nt] = (unsigned)(nb + nt * 16 + lrow) * 128 + lgrp * 8;
    __syncthreads();

    f32x4 acc1[2][2];
    #pragma unroll
    for (int mt = 0; mt < 2; ++mt) {
        const int cb = wc * 32 + mt * 16 + lgrp * 4;
        #pragma unroll
        for (int nt = 0; nt < 2; ++nt) {
            acc1[mt][nt][0] = gb1[cb];     acc1[mt][nt][1] = gb1[cb + 1];
            acc1[mt][nt][2] = gb1[cb + 2]; acc1[mt][nt][3] = gb1[cb + 3];
        }
    }
    {
        auto ldA = [&](int s, bf16x8* dst) {
            #pragma unroll
            for (int mt = 0; mt < 2; ++mt)
                dst[mt] = *(const bf16x8*)(w1q + (size_t)((s * 8 + wc * 2 + mt) * 64 + l) * 8);
        };
        auto ldB = [&](int s, bf16x8* dst) {
            #pragma unroll
            for (int nt = 0; nt < 2; ++nt)
                dst[nt] = *(const bf16x8*)(h_bf + offN[nt] + s * 32);
        };
        bf16x8 aB[2][2], bB[2][2];
        ldA(0, aB[0]); ldB(0, bB[0]);
        ldA(1, aB[1]); ldB(1, bB[1]);
        #pragma unroll
        for (int s = 0; s < 4; ++s) {
            const int c = s & 1;
            #pragma unroll
            for (int mt = 0; mt < 2; ++mt)
                #pragma unroll
                for (int nt = 0; nt < 2; ++nt)
                    acc1[mt][nt] = __builtin_amdgcn_mfma_f32_16x16x32_bf16(aB[c][mt], bB[c][nt], acc1[mt][nt], 0, 0, 0);
            if (s < 2) { ldA(s + 2, aB[c]); ldB(s + 2, bB[c]); }
        }
    }

    float2 myln[2];
    #pragma unroll
    for (int nt = 0; nt < 2; ++nt) {
        float p1 = 0.f, p2 = 0.f;
        #pragma unroll
        for (int mt = 0; mt < 2; ++mt)
            #pragma unroll
            for (int r = 0; r < 4; ++r) { float v = acc1[mt][nt][r]; p1 += v; p2 += v * v; }
        p1 += __shfl_xor(p1, 16); p2 += __shfl_xor(p2, 16);
        p1 += __shfl_xor(p1, 32); p2 += __shfl_xor(p2, 32);
        myln[nt] = make_float2(p1, p2);
        if (l < 16) lnb[wc][nt * 16 + l] = myln[nt];
    }
    __syncthreads();

    #pragma unroll
    for (int nt = 0; nt < 2; ++nt) {
        const int el = nt * 16 + lrow;
        float2 a0 = lnb[0][el], a1 = lnb[1][el], a2 = lnb[2][el], a3 = lnb[3][el];
        const float s1 = a0.x + a1.x + a2.x + a3.x;
        const float s2 = a0.y + a1.y + a2.y + a3.y;
        const float mu = s1 * (1.f / 128.f);
        const float rs = rsqrtf(s2 * (1.f / 128.f) - mu * mu + LN_EPS);
        #pragma unroll
        for (int mt = 0; mt < 2; ++mt) {
            const int cb = wc * 32 + mt * 16 + lgrp * 4;
            const float2 g0 = gbe[cb], g1 = gbe[cb+1], g2 = gbe[cb+2], g3 = gbe[cb+3];
            ushort4 u;
            u.x = f2bf(fmaxf((acc1[mt][nt][0] - mu) * rs * g0.x + g0.y, 0.f));
            u.y = f2bf(fmaxf((acc1[mt][nt][1] - mu) * rs * g1.x + g1.y, 0.f));
            u.z = f2bf(fmaxf((acc1[mt][nt][2] - mu) * rs * g2.x + g2.y, 0.f));
            u.w = f2bf(fmaxf((acc1[mt][nt][3] - mu) * rs * g3.x + g3.y, 0.f));
            *(ushort4*)(hsq + ((cb >> 3) * 32 + el) * 16 + (lgrp & 1) * 8) = u;
        }
    }
    __syncthreads();

    f32x4 acc2[2][2];
    #pragma unroll
    for (int km = 0; km < 2; ++km) {
        const int c2 = (wc * 2 + km) * 16 + lgrp * 4;
        #pragma unroll
        for (int nt = 0; nt < 2; ++nt) {
            acc2[km][nt][0] = gb2[c2];     acc2[km][nt][1] = gb2[c2 + 1];
            acc2[km][nt][2] = gb2[c2 + 2]; acc2[km][nt][3] = gb2[c2 + 3];
        }
    }
    {
        bf16x8 a0C = *(const bf16x8*)(w2q + (size_t)((wc * 2) * 64 + l) * 8);
        bf16x8 a1C = *(const bf16x8*)(w2q + (size_t)((wc * 2 + 1) * 64 + l) * 8);
        #pragma unroll
        for (int s2 = 0; s2 < 4; ++s2) {
            bf16x8 a0N, a1N;
            if (s2 < 3) {
                a0N = *(const bf16x8*)(w2q + (size_t)(((s2+1) * 8 + wc * 2) * 64 + l) * 8);
                a1N = *(const bf16x8*)(w2q + (size_t)(((s2+1) * 8 + wc * 2 + 1) * 64 + l) * 8);
            }
            bf16x8 hb[2];
            #pragma unroll
            for (int nt = 0; nt < 2; ++nt)
                hb[nt] = *(const bf16x8*)(hsq + (((s2 * 4 + lgrp) * 32) + nt * 16 + lrow) * 16);
            #pragma unroll
            for (int nt = 0; nt < 2; ++nt) {
                acc2[0][nt] = __builtin_amdgcn_mfma_f32_16x16x32_bf16(a0C, hb[nt], acc2[0][nt], 0, 0, 0);
                acc2[1][nt] = __builtin_amdgcn_mfma_f32_16x16x32_bf16(a1C, hb[nt], acc2[1][nt], 0, 0, 0);
            }
            a0C = a0N; a1C = a1N;
        }
    }
    #pragma unroll
    for (int km = 0; km < 2; ++km) {
        const int c2 = (wc * 2 + km) * 16 + lgrp * 4;
        #pragma unroll
        for (int nt = 0; nt < 2; ++nt) {
            const int el = nt * 16 + lrow;
            ushort4 o;
            o.x = f2bf(acc2[km][nt][0]); o.y = f2bf(acc2[km][nt][1]);
            o.z = f2bf(acc2[km][nt][2]); o.w = f2bf(acc2[km][nt][3]);
            *(ushort4*)(q_bf + (size_t)(nb + el) * 128 + c2) = o;
        }
    }
}

// ------------- Kernel B: edge kernel — line-coalesced gathers, LDS-staged X-sum & q -------------
__global__ __launch_bounds__(256, 3) void edge_kernel(
    const unsigned short* __restrict__ feats_bf,
    const int*   __restrict__ eidx,
    const float* __restrict__ ew_pre,
    const unsigned short* __restrict__ Hd, const unsigned short* __restrict__ Hs,
    const float* __restrict__ kB1, const float* __restrict__ kG, const float* __restrict__ kBE,
    const float* __restrict__ vB1, const float* __restrict__ vG, const float* __restrict__ vBE,
    const float* __restrict__ kB2, const float* __restrict__ vB2,
    const unsigned short* __restrict__ w1fp, const unsigned short* __restrict__ w2p,
    const unsigned short* __restrict__ q_bf,
    float* __restrict__ ex_out, float* __restrict__ vw_out, float* __restrict__ denom)
{
    __shared__ __align__(16) unsigned char xhs[16384]; // xs (Hd+Hs sums), later hs (hidden)
    __shared__ __align__(16) unsigned char qs[8448];   // q rows: 32 x 264B (padded stride)
    __shared__ float2 lnb[4][32];
    __shared__ float  gb1[256];
    __shared__ float2 gbe[256];
    __shared__ float  gb2[144];
    __shared__ float  ew_s[32];

    const int t = threadIdx.x;
    const int eb = blockIdx.x * 32;
    const int wc = t >> 6, l = t & 63, lrow = l & 15, lgrp = l >> 4;

    // ---- line-coalesced gathers: 8 lanes own one edge row, 8 consecutive 16B chunks ----
    const int el8 = t >> 3;     // edge 0..31
    const int ch8 = t & 7;      // chunk lane 0..7
    const int d8 = eidx[NE + eb + el8];
    const int s8 = eidx[eb + el8];
    int4 gd[4], gs4[4];
    #pragma unroll
    for (int p = 0; p < 4; ++p)
        gd[p] = *(const int4*)(Hd + (size_t)d8 * 256 + (p * 8 + ch8) * 8);
    #pragma unroll
    for (int p = 0; p < 4; ++p)
        gs4[p] = *(const int4*)(Hs + (size_t)s8 * 256 + (p * 8 + ch8) * 8);

    // q rows coalesced: round m covers 16 edges, 4 lanes x 64B contiguous per row
    int4 gq[2]; int elq[2];
    #pragma unroll
    for (int m = 0; m < 2; ++m) {
        elq[m] = m * 16 + (t >> 4);
        const int chq = t & 15;
        const int dq = eidx[NE + eb + elq[m]];
        gq[m] = *(const int4*)(q_bf + (size_t)dq * 128 + chq * 8);
    }

    // feats B fragment, w1f A fragments, dst for atomics
    bf16x8 bF[2];
    int dst01[2];
    #pragma unroll
    for (int nt = 0; nt < 2; ++nt) {
        const int e = eb + nt * 16 + lrow;
        bF[nt] = *(const bf16x8*)(feats_bf + (size_t)e * 32 + lgrp * 8);
        dst01[nt] = eidx[NE + e];
    }
    bf16x8 aF[4];
    #pragma unroll
    for (int mt = 0; mt < 4; ++mt)
        aF[mt] = *(const bf16x8*)(w1fp + (size_t)((wc * 4 + mt) * 64 + l) * 8);

    gb1[t] = (t < 128) ? kB1[t] : vB1[t - 128];
    gbe[t] = make_float2((t < 128) ? kG[t] : vG[t - 128],
                         (t < 128) ? kBE[t] : vBE[t - 128]);
    if (t < 144) gb2[t] = (t < 128) ? kB2[t] : vB2[t - 128];
    if (t < 32) ew_s[t] = ew_pre[eb + t];

    // sum Hd+Hs (packed fp16) -> xs; q -> qs
    #pragma unroll
    for (int p = 0; p < 4; ++p) {
        const int chunk = p * 8 + ch8;
        half8_ a = __builtin_bit_cast(half8_, gd[p]);
        half8_ b = __builtin_bit_cast(half8_, gs4[p]);
        *(half8_*)(xhs + (chunk * 32 + el8) * 16) = a + b;
    }
    #pragma unroll
    for (int m = 0; m < 2; ++m)
        *(int4*)(qs + elq[m] * 264 + (t & 15) * 16) = gq[m];
    __syncthreads();   // B0

    // ---- GEMM-feats (K=32) into bias-initialized acc ----
    f32x4 acc1[4][2];
    #pragma unroll
    for (int mt = 0; mt < 4; ++mt) {
        const int cb = wc * 64 + mt * 16 + lgrp * 4;
        #pragma unroll
        for (int nt = 0; nt < 2; ++nt) {
            acc1[mt][nt][0] = gb1[cb];     acc1[mt][nt][1] = gb1[cb + 1];
            acc1[mt][nt][2] = gb1[cb + 2]; acc1[mt][nt][3] = gb1[cb + 3];
        }
    }
    #pragma unroll
    for (int mt = 0; mt < 4; ++mt)
        #pragma unroll
        for (int nt = 0; nt < 2; ++nt)
            acc1[mt][nt] = __builtin_amdgcn_mfma_f32_16x16x32_bf16(aF[mt], bF[nt], acc1[mt][nt], 0, 0, 0);

    // ---- hidden assembly: += (Hd[dst]+Hs[src]) from xs ----
    #pragma unroll
    for (int mt = 0; mt < 4; ++mt) {
        const int cb = wc * 64 + mt * 16 + lgrp * 4;
        const int chunk = cb >> 3;
        const int hoff = (lgrp & 1) * 8;
        #pragma unroll
        for (int nt = 0; nt < 2; ++nt) {
            const int el = nt * 16 + lrow;
            half4_ hv = *(const half4_*)(xhs + (chunk * 32 + el) * 16 + hoff);
            acc1[mt][nt][0] += (float)hv[0];
            acc1[mt][nt][1] += (float)hv[1];
            acc1[mt][nt][2] += (float)hv[2];
            acc1[mt][nt][3] += (float)hv[3];
        }
    }

    // ---- LN partials ----
    float2 myln[2];
    #pragma unroll
    for (int nt = 0; nt < 2; ++nt) {
        float p1 = 0.f, p2 = 0.f;
        #pragma unroll
        for (int mt = 0; mt < 4; ++mt)
            #pragma unroll
            for (int r = 0; r < 4; ++r) { float v = acc1[mt][nt][r]; p1 += v; p2 += v * v; }
        p1 += __shfl_xor(p1, 16); p2 += __shfl_xor(p2, 16);
        p1 += __shfl_xor(p1, 32); p2 += __shfl_xor(p2, 32);
        myln[nt] = make_float2(p1, p2);
        if (l < 16) lnb[wc][nt * 16 + l] = myln[nt];
    }
    __syncthreads();   // B1 (also: all xs reads complete -> safe to overlay hs)

    // ---- normalize + ReLU + bf16 -> hs (overlaid on xs region) ----
    #pragma unroll
    for (int nt = 0; nt < 2; ++nt) {
        const int el = nt * 16 + lrow;
        const float2 oth = lnb[wc ^ 1][el];
        const float s1 = myln[nt].x + oth.x, s2 = myln[nt].y + oth.y;
        const float mu = s1 * (1.f / 128.f);
        const float rs = rsqrtf(s2 * (1.f / 128.f) - mu * mu + LN_EPS);
        #pragma unroll
        for (int mt = 0; mt < 4; ++mt) {
            const int cb = wc * 64 + mt * 16 + lgrp * 4;
            const int region = cb >> 7, kc = cb & 127;
            const float2 g0 = gbe[cb], g1 = gbe[cb+1], g2 = gbe[cb+2], g3 = gbe[cb+3];
            ushort4 u;
            u.x = f2bf(fmaxf((acc1[mt][nt][0] - mu) * rs * g0.x + g0.y, 0.f));
            u.y = f2bf(fmaxf((acc1[mt][nt][1] - mu) * rs * g1.x + g1.y, 0.f));
            u.z = f2bf(fmaxf((acc1[mt][nt][2] - mu) * rs * g2.x + g2.y, 0.f));
            u.w = f2bf(fmaxf((acc1[mt][nt][3] - mu) * rs * g3.x + g3.y, 0.f));
            *(ushort4*)(xhs + region * 8192 + ((kc >> 3) * 32 + el) * 16 + (lgrp & 1) * 8) = u;
        }
    }
    __syncthreads();   // B2

    // ---- GEMM2: kT[128][32e] + vT[16][32e], K=128 (4 steps), A depth-2 from L2 ----
    f32x4 acc2[2][2], accv;
    #pragma unroll
    for (int km = 0; km < 2; ++km) {
        const int c0b = (wc * 2 + km) * 16 + lgrp * 4;
        #pragma unroll
        for (int nt = 0; nt < 2; ++nt) {
            acc2[km][nt][0] = gb2[c0b];     acc2[km][nt][1] = gb2[c0b + 1];
            acc2[km][nt][2] = gb2[c0b + 2]; acc2[km][nt][3] = gb2[c0b + 3];
        }
    }
    const int vel = wc * 16 + lrow;   // valid when wc<2
    {
        const int cv = 128 + lgrp * 4;
        accv[0] = gb2[cv]; accv[1] = gb2[cv+1]; accv[2] = gb2[cv+2]; accv[3] = gb2[cv+3];
    }
    {
        bf16x8 a0C = *(const bf16x8*)(w2p + (size_t)((wc * 2) * 64 + l) * 8);
        bf16x8 a1C = *(const bf16x8*)(w2p + (size_t)((wc * 2 + 1) * 64 + l) * 8);
        bf16x8 avC = *(const bf16x8*)(w2p + (size_t)(8 * 64 + l) * 8);
        #pragma unroll
        for (int s2 = 0; s2 < 4; ++s2) {
            bf16x8 a0N, a1N, avN;
            if (s2 < 3) {
                a0N = *(const bf16x8*)(w2p + (size_t)(((s2+1) * 9 + wc * 2) * 64 + l) * 8);
                a1N = *(const bf16x8*)(w2p + (size_t)(((s2+1) * 9 + wc * 2 + 1) * 64 + l) * 8);
                avN = *(const bf16x8*)(w2p + (size_t)(((s2+1) * 9 + 8) * 64 + l) * 8);
            }
            bf16x8 hb[2];
            #pragma unroll
            for (int nt = 0; nt < 2; ++nt)
                hb[nt] = *(const bf16x8*)(xhs + ((s2 * 4 + lgrp) * 32 + nt * 16 + lrow) * 16);
            #pragma unroll
            for (int nt = 0; nt < 2; ++nt) {
                acc2[0][nt] = __builtin_amdgcn_mfma_f32_16x16x32_bf16(a0C, hb[nt], acc2[0][nt], 0, 0, 0);
                acc2[1][nt] = __builtin_amdgcn_mfma_f32_16x16x32_bf16(a1C, hb[nt], acc2[1][nt], 0, 0, 0);
            }
            if (wc < 2) {
                bf16x8 hv = *(const bf16x8*)(xhs + 8192 + ((s2 * 4 + lgrp) * 32 + vel) * 16);
                accv = __builtin_amdgcn_mfma_f32_16x16x32_bf16(avC, hv, accv, 0, 0, 0);
            }
            a0C = a0N; a1C = a1N; avC = avN;
        }
    }

    // ---- v output ----
    if (wc < 2) {
        const float sc = ew_s[vel];
        float4 vo;
        vo.x = accv[0] * sc; vo.y = accv[1] * sc; vo.z = accv[2] * sc; vo.w = accv[3] * sc;
        *(float4*)(vw_out + (size_t)(eb + vel) * 16 + lgrp * 4) = vo;
    }

    // ---- scores + exp + denom atomics (q from LDS, padded stride) ----
    #pragma unroll
    for (int km = 0; km < 2; ++km) {
        #pragma unroll
        for (int nt = 0; nt < 2; ++nt) {
            const int el = nt * 16 + lrow;
            const int c0 = (wc * 2 + km) * 16 + lgrp * 4;
            const int2 qv = *(const int2*)(qs + el * 264 + c0 * 2);
            const float q0 = bf2f((unsigned short)(qv.x & 0xffff));
            const float q1 = bf2f((unsigned short)(((unsigned)qv.x) >> 16));
            const float q2 = bf2f((unsigned short)(qv.y & 0xffff));
            const float q3 = bf2f((unsigned short)(((unsigned)qv.y) >> 16));
            float sp = acc2[km][nt][0] * q0 + acc2[km][nt][1] * q1
                     + acc2[km][nt][2] * q2 + acc2[km][nt][3] * q3;
            sp += __shfl_xor(sp, 16);
            if ((l & 16) == 0) {
                const float exv = expf(sp * INV_SQRT_HD);
                const int hh = (wc * 2 + km) * 2 + (lgrp >> 1);
                ex_out[(size_t)(eb + el) * 16 + hh] = exv;
                atomicAdd(&denom[(size_t)dst01[nt] * 16 + hh], exv);
            }
        }
    }
}

// ------------- Kernel C: alpha = ex/denom, scatter out += sum_h(alpha*vw)*rel_x -------------
__global__ __launch_bounds__(256) void finalize_kernel(
    const int* __restrict__ eidx, const float* __restrict__ relx,
    const float* __restrict__ exb, const float* __restrict__ vwb,
    const float* __restrict__ den, float* __restrict__ out)
{
    const int e = blockIdx.x * 256 + threadIdx.x;
    const int dst = eidx[NE + e];
    const float4* ex4 = (const float4*)(exb + (size_t)e*16);
    const float4* vw4 = (const float4*)(vwb + (size_t)e*16);
    const float4* dn4 = (const float4*)(den + (size_t)dst*16);
    float s = 0.f;
    #pragma unroll
    for (int k = 0; k < 4; ++k) {
        float4 a = ex4[k], b = vw4[k], d = dn4[k];
        s += (a.x/d.x)*b.x + (a.y/d.y)*b.y + (a.z/d.z)*b.z + (a.w/d.w)*b.w;
    }
    float r0 = relx[(size_t)e*3+0], r1 = relx[(size_t)e*3+1], r2 = relx[(size_t)e*3+2];
    atomicAdd(&out[(size_t)dst*3+0], s*r0);
    atomicAdd(&out[(size_t)dst*3+1], s*r1);
    atomicAdd(&out[(size_t)dst*3+2], s*r2);
}

extern "C" void kernel_launch(void* const* d_in, const int* in_sizes, int n_in,
                              void* d_out, int out_size, void* d_ws, size_t ws_size,
                              hipStream_t stream) {
    const float* h         = (const float*)d_in[0];
    const float* rel_x     = (const float*)d_in[1];
    const float* r_feat    = (const float*)d_in[2];
    const float* edge_feat = (const float*)d_in[3];
    const int*   eidx      = (const int*)  d_in[4];
    const float* kW1 = (const float*)d_in[5];
    const float* kB1 = (const float*)d_in[6];
    const float* kG  = (const float*)d_in[7];
    const float* kBE = (const float*)d_in[8];
    const float* kW2 = (const float*)d_in[9];
    const float* kB2 = (const float*)d_in[10];
    const float* vW1 = (const float*)d_in[11];
    const float* vB1 = (const float*)d_in[12];
    const float* vG  = (const float*)d_in[13];
    const float* vBE = (const float*)d_in[14];
    const float* vW2 = (const float*)d_in[15];
    const float* vB2 = (const float*)d_in[16];
    const float* qW1 = (const float*)d_in[17];
    const float* qB1 = (const float*)d_in[18];
    const float* qG  = (const float*)d_in[19];
    const float* qBE = (const float*)d_in[20];
    const float* qW2 = (const float*)d_in[21];
    const float* qB2 = (const float*)d_in[22];
    const float* ewW = (const float*)d_in[23];
    const float* ewB = (const float*)d_in[24];

    float* ws   = (float*)d_ws;
    float* qbuf = ws;                             // bf16 q lives here (N*128)
    float* exb  = qbuf + (size_t)NN*128;          // E*16
    float* vwb  = exb + (size_t)NE*16;            // E*16
    float* den  = vwb + (size_t)NE*16;            // N*16
    float* ewp  = den + (size_t)NN*16;            // E
    unsigned short* w1fp = (unsigned short*)(ewp + (size_t)NE);   // 8192
    unsigned short* w1d  = w1fp + 8192;                           // 32768
    unsigned short* w1s  = w1d + 32768;                           // 32768
    unsigned short* w2p  = w1s + 32768;                           // 18432
    unsigned short* w1q  = w2p + 18432;                           // 16384
    unsigned short* w2q  = w1q + 16384;                           // 16384
    unsigned short* h_bf = w2q + 16384;                           // N*128
    unsigned short* feats_bf = h_bf + (size_t)NN*128;             // E*32
    unsigned short* Hd   = feats_bf + (size_t)NE*32;              // N*256 fp16
    unsigned short* Hs   = Hd + (size_t)NN*256;                   // N*256 fp16
    unsigned short* q_bf = (unsigned short*)qbuf;                 // N*128 bf16
    float* outf = (float*)d_out;

    hipMemsetAsync(den, 0, (size_t)NN*16*sizeof(float), stream);
    hipMemsetAsync(outf, 0, (size_t)NN*3*sizeof(float), stream);

    prep_kernel<<<2488, 256, 0, stream>>>(h, r_feat, edge_feat, ewW, ewB,
                                          kW1, vW1, kW2, vW2, qW1, qW2,
                                          h_bf, feats_bf, ewp,
                                          w1fp, w1d, w1s, w2p, w1q, w2q);
    hprep_kernel<<<NN/32, 256, 0, stream>>>(h_bf, w1d, w1s, Hd, Hs);
    qmlp_kernel<<<NN/32, 256, 0, stream>>>(h_bf, qB1, qG, qBE, qB2, w1q, w2q, q_bf);
    edge_kernel<<<NE/32, 256, 0, stream>>>(feats_bf, eidx, ewp,
                                           Hd, Hs,
                                           kB1, kG, kBE, vB1, vG, vBE,
                                           kB2, vB2, w1fp, w2p, q_bf,
                                           exb, vwb, den);
    finalize_kernel<<<NE/256, 256, 0, stream>>>(eidx, rel_x, exb, vwb, den, outf);
}